// Round 15
// baseline (248.606 us; speedup 1.0000x reference)
//
#include <hip/hip_runtime.h>

#define HDIM 128
#define NGRAPH 64
#define NCLASS 7
#define MAXB 2048     // max 64-node buckets: supports n <= 131072

typedef __attribute__((ext_vector_type(8))) __bf16 bf16x8;
typedef __attribute__((ext_vector_type(4))) float f32x4;

__device__ __forceinline__ unsigned short bf16_rne(float f) {
  unsigned u = __float_as_uint(f);
  u += 0x7FFF + ((u >> 16) & 1);
  return (unsigned short)(u >> 16);
}

// async global->LDS 16B (direct-to-LDS, no VGPR round-trip). LDS dest must be
// wave-uniform base + lane*16 (our staging layouts satisfy this by construction).
__device__ __forceinline__ void gload16(const void* g, void* l) {
  __builtin_amdgcn_global_load_lds((const __attribute__((address_space(1))) void*)g,
                                   (__attribute__((address_space(3))) void*)l, 16, 0, 0);
}

// ---------------- ZERO-FABRIC-ATOMIC preprocessing (R8/R9) ----------------

// count pass: per-block LDS bucket histograms -> PRIVATE rows of hist[cB][NB] (no merges)
__global__ void k_countw(const int* __restrict__ col, const int* __restrict__ row, int E,
                         int* __restrict__ histI, int* __restrict__ histO,
                         const float* __restrict__ W,
                         unsigned short* __restrict__ wthi, unsigned short* __restrict__ wtlo,
                         int cB, int NB) {
  int b = blockIdx.x;
  if (b < cB) {
    __shared__ int binsI[MAXB], binsO[MAXB];
    int t = threadIdx.x;
    for (int i = t; i < NB; i += 256) { binsI[i] = 0; binsO[i] = 0; }
    __syncthreads();
    int base = b << 11;  // 2048 contiguous edges per block
#pragma unroll
    for (int j = 0; j < 8; j++) {
      int e = base + (j << 8) + t;
      if (e < E) {
        atomicAdd(&binsI[col[e] >> 6], 1);  // LDS only
        atomicAdd(&binsO[row[e] >> 6], 1);
      }
    }
    __syncthreads();
    for (int i = t; i < NB; i += 256) {
      histI[(size_t)b * NB + i] = binsI[i];  // plain coalesced writes
      histO[(size_t)b * NB + i] = binsO[i];
    }
  } else {
    int idx = (b - cB) * 256 + threadIdx.x;  // 0..16383
    int c = idx >> 7, k = idx & 127;
    float v = W[k * 128 + c];
    unsigned short h = bf16_rne(v);
    wthi[idx] = h;
    wtlo[idx] = bf16_rne(v - __uint_as_float((unsigned)h << 16));
  }
}

// segment scan: thread=(bucket, 8-row segment), register-staged loads (R9 fix).
__global__ void k_hA(int* __restrict__ histI, int* __restrict__ histO,
                     int* __restrict__ segI, int* __restrict__ segO,
                     int NB, int cB) {
  int bkt = blockIdx.x * 256 + threadIdx.x;
  if (bkt >= NB) return;
  int* hist = blockIdx.z ? histO : histI;
  int* segs = blockIdx.z ? segO : segI;
  int r0 = blockIdx.y << 3;
  int v[8];
#pragma unroll
  for (int j = 0; j < 8; j++) {
    int ri = r0 + j;
    v[j] = (ri < cB) ? hist[(size_t)ri * NB + bkt] : 0;
  }
  int s = 0;
#pragma unroll
  for (int j = 0; j < 8; j++) { int tv = v[j]; v[j] = s; s += tv; }
#pragma unroll
  for (int j = 0; j < 8; j++) {
    int ri = r0 + j;
    if (ri < cB) hist[(size_t)ri * NB + bkt] = v[j];
  }
  segs[(size_t)blockIdx.y * NB + bkt] = s;
}

// per-bucket scan of segment sums (register-chunked) -> seg bases + bucket totals
__global__ void k_hB(int* __restrict__ segI, int* __restrict__ segO,
                     int* __restrict__ btotI, int* __restrict__ btotO,
                     int NB, int NSEG) {
  int bkt = blockIdx.x * 256 + threadIdx.x;
  if (bkt >= NB) return;
  int* segs = blockIdx.y ? segO : segI;
  int* btot = blockIdx.y ? btotO : btotI;
  int run = 0;
  for (int c0 = 0; c0 < NSEG; c0 += 8) {
    int v[8];
#pragma unroll
    for (int j = 0; j < 8; j++) {
      int si = c0 + j;
      v[j] = (si < NSEG) ? segs[(size_t)si * NB + bkt] : 0;
    }
#pragma unroll
    for (int j = 0; j < 8; j++) { int tv = v[j]; v[j] = run; run += tv; }
#pragma unroll
    for (int j = 0; j < 8; j++) {
      int si = c0 + j;
      if (si < NSEG) segs[(size_t)si * NB + bkt] = v[j];
    }
  }
  btot[bkt] = run;
}

// single-block dual scan: bucket totals -> boff (exclusive, +E at [NB])
__global__ void k_hscanB(const int* __restrict__ btotI, int* __restrict__ boffI,
                         const int* __restrict__ btotO, int* __restrict__ boffO,
                         int NB, int E) {
  __shared__ int sh[1024];
  int t = threadIdx.x;
  for (int s = 0; s < 2; s++) {
    const int* src = s ? btotO : btotI;
    int* boff = s ? boffO : boffI;
    int i0 = 2 * t, i1 = 2 * t + 1;
    int a0 = (i0 < NB) ? src[i0] : 0;
    int a1 = (i1 < NB) ? src[i1] : 0;
    sh[t] = a0 + a1;
    __syncthreads();
    for (int o = 1; o < 1024; o <<= 1) {
      int v = (t >= o) ? sh[t - o] : 0;
      __syncthreads();
      sh[t] += v;
      __syncthreads();
    }
    int ex = (t == 0) ? 0 : sh[t - 1];
    if (i0 < NB) boff[i0] = ex;
    if (i1 < NB) boff[i1] = ex + a0;
    if (t == 0) boff[NB] = E;
    __syncthreads();
  }
}

// fill pass: positions entirely from LDS (boff + seg base + my-block rel + LDS rank).
__global__ void __launch_bounds__(256) k_fill(const int* __restrict__ row,
                                              const int* __restrict__ col, int E,
                                              const int* __restrict__ histI,
                                              const int* __restrict__ histO,
                                              const int* __restrict__ segI,
                                              const int* __restrict__ segO,
                                              const int* __restrict__ boffI,
                                              const int* __restrict__ boffO,
                                              int* __restrict__ inBL,
                                              int* __restrict__ outBL, int NB) {
  __shared__ int baseI[MAXB], baseO[MAXB], binsI[MAXB], binsO[MAXB];  // 32 KB
  int t = threadIdx.x, b = blockIdx.x;
  int sg = b >> 3;
  for (int i = t; i < NB; i += 256) {
    baseI[i] = boffI[i] + segI[(size_t)sg * NB + i] + histI[(size_t)b * NB + i];
    baseO[i] = boffO[i] + segO[(size_t)sg * NB + i] + histO[(size_t)b * NB + i];
    binsI[i] = 0;
    binsO[i] = 0;
  }
  __syncthreads();
  int base = b << 11;
#pragma unroll
  for (int j = 0; j < 8; j++) {
    int e = base + (j << 8) + t;
    if (e < E) {
      int r = row[e], c = col[e];
      int rkI = atomicAdd(&binsI[c >> 6], 1);  // LDS only
      int rkO = atomicAdd(&binsO[r >> 6], 1);
      inBL[baseI[c >> 6] + rkI] = (r << 6) | (c & 63);
      outBL[baseO[r >> 6] + rkO] = (c << 6) | (r & 63);
    }
  }
}

// per-bucket: count per-node (=> deg/dinv), LDS scan, node-CSR reorder into gwi,
// write od/dx with ABSOLUTE offsets.
__global__ void __launch_bounds__(256) k_rank2x(const int* __restrict__ inBL,
                                                const int* __restrict__ boffI,
                                                const int* __restrict__ batch,
                                                const float* __restrict__ x,
                                                int2* __restrict__ od,
                                                float2* __restrict__ dx,
                                                int* __restrict__ gwi, int n) {
  __shared__ int cnt[64], cnt2[64], loc[64], sc[64];
  int bi = blockIdx.x, t = threadIdx.x;
  if (t < 64) { cnt[t] = 0; cnt2[t] = 0; }
  __syncthreads();
  int e0 = boffI[bi], e1 = boffI[bi + 1];
  for (int e = e0 + t; e < e1; e += 256) atomicAdd(&cnt[inBL[e] & 63], 1);
  __syncthreads();
  if (t < 64) sc[t] = cnt[t];
  __syncthreads();
  for (int o = 1; o < 64; o <<= 1) {
    int v = (t < 64 && t >= o) ? sc[t - o] : 0;
    __syncthreads();
    if (t < 64) sc[t] += v;
    __syncthreads();
  }
  if (t < 64) {
    int excl = (t == 0) ? 0 : sc[t - 1];
    loc[t] = e0 + excl;
    int node = (bi << 6) + t;
    if (node < n) {
      int g = batch[node];
      float dinv = rsqrtf((float)(cnt[t] + 1));  // +1 self-loop
      od[node] = make_int2((e0 + excl) | (g << 24), __float_as_int(dinv));
      dx[node] = make_float2(dinv, x[node]);
    }
  }
  __syncthreads();
  for (int e = e0 + t; e < e1; e += 256) {
    int v = inBL[e];
    int dl = v & 63;
    int k = atomicAdd(&cnt2[dl], 1);
    gwi[loc[dl] + k] = v >> 6;
  }
}

// layer-1 aggregate by GATHER over in-CSR:
// sd[i] = { dinv^2 x_i + dinv * sum_r dinv_r x_r , dinv }
__global__ void k_s(const int2* __restrict__ od, const float2* __restrict__ dx,
                    const int* __restrict__ gwi, float2* __restrict__ sd, int n, int E) {
  int i = blockIdx.x * 256 + threadIdx.x;
  if (i >= n) return;
  int2 o2 = od[i];
  float dinv = __int_as_float(o2.y);
  int e0 = o2.x & 0xFFFFFF;
  int e1 = (i + 1 < n) ? (od[i + 1].x & 0xFFFFFF) : E;
  float s0 = 0.f, s1 = 0.f;
  int e = e0;
  for (; e + 2 <= e1; e += 2) {
    float2 a = dx[gwi[e]];
    float2 b = dx[gwi[e + 1]];
    s0 = fmaf(a.x, a.y, s0);
    s1 = fmaf(b.x, b.y, s1);
  }
  if (e < e1) { float2 a = dx[gwi[e]]; s0 = fmaf(a.x, a.y, s0); }
  float xv = dx[i].y;
  sd[i] = make_float2(fmaf(dinv * dinv, xv, dinv * (s0 + s1)), dinv);
}

// ---------------- fused: h1 = relu(s*W1+b1) recomputed per edge + agg2 ----------------
// Lane-parallel edge gather + register broadcast (R4). Output z as bf16 hi/lo.

__global__ void __launch_bounds__(256) k_l2in(const float2* __restrict__ sd,
                                              const int2* __restrict__ od,
                                              const int* __restrict__ gwi,
                                              const float* __restrict__ W1,
                                              const float* __restrict__ b1,
                                              ushort2* __restrict__ zhi,
                                              ushort2* __restrict__ zlo, int n, int E) {
  int node = blockIdx.x * 4 + (threadIdx.x >> 6);
  if (node >= n) return;
  int l = threadIdx.x & 63;
  float2 w1 = ((const float2*)W1)[l];
  float2 bv = ((const float2*)b1)[l];
  int2 on = od[node];
  float dstd = __int_as_float(on.y);
  float nself = dstd * dstd;
  float sv = sd[node].x;
  float2 acc;
  acc.x = nself * fmaxf(fmaf(sv, w1.x, bv.x), 0.f);
  acc.y = nself * fmaxf(fmaf(sv, w1.y, bv.y), 0.f);
  int e0 = on.x & 0xFFFFFF;
  int e1 = (node + 1 < n) ? (od[node + 1].x & 0xFFFFFF) : E;

  for (int eb = e0; eb < e1; eb += 64) {
    int m = e1 - eb; if (m > 64) m = 64;
    int ee = eb + l; if (ee >= e1) ee = e1 - 1;      // clamped, coalesced
    float2 q = sd[gwi[ee]];                          // per-lane independent gather
    float u = q.y * dstd;
    int k = 0;
    for (; k + 4 <= m; k += 4) {
      float q0 = __shfl(q.x, k),     u0 = __shfl(u, k);
      float q1 = __shfl(q.x, k + 1), u1 = __shfl(u, k + 1);
      float q2 = __shfl(q.x, k + 2), u2 = __shfl(u, k + 2);
      float q3 = __shfl(q.x, k + 3), u3 = __shfl(u, k + 3);
      acc.x = fmaf(u0, fmaxf(fmaf(q0, w1.x, bv.x), 0.f), acc.x);
      acc.y = fmaf(u0, fmaxf(fmaf(q0, w1.y, bv.y), 0.f), acc.y);
      acc.x = fmaf(u1, fmaxf(fmaf(q1, w1.x, bv.x), 0.f), acc.x);
      acc.y = fmaf(u1, fmaxf(fmaf(q1, w1.y, bv.y), 0.f), acc.y);
      acc.x = fmaf(u2, fmaxf(fmaf(q2, w1.x, bv.x), 0.f), acc.x);
      acc.y = fmaf(u2, fmaxf(fmaf(q2, w1.y, bv.y), 0.f), acc.y);
      acc.x = fmaf(u3, fmaxf(fmaf(q3, w1.x, bv.x), 0.f), acc.x);
      acc.y = fmaf(u3, fmaxf(fmaf(q3, w1.y, bv.y), 0.f), acc.y);
    }
    for (; k < m; k++) {
      float qk = __shfl(q.x, k), uk = __shfl(u, k);
      acc.x = fmaf(uk, fmaxf(fmaf(qk, w1.x, bv.x), 0.f), acc.x);
      acc.y = fmaf(uk, fmaxf(fmaf(qk, w1.y, bv.y), 0.f), acc.y);
    }
  }

  ushort2 h, lo;
  h.x = bf16_rne(acc.x);
  lo.x = bf16_rne(acc.x - __uint_as_float((unsigned)h.x << 16));
  h.y = bf16_rne(acc.y);
  lo.y = bf16_rne(acc.y - __uint_as_float((unsigned)h.y << 16));
  zhi[(size_t)node * 64 + l] = h;
  zlo[(size_t)node * 64 + l] = lo;
}

// ---------------- FUSED layer-2 GEMM + layer-3 pool ----------------
// R14: pool j-SPLIT to shrink LDS 49.7KB -> 33.3KB -> 4 blocks/CU (was 3). Evidence:
// kernel is stall-dominated (MfmaUtil 6%, VALU 25%, occ 14%, 970 GB/s on 58.9MB);
// bank conflicts are negligible (420k cycles / 256 CUs = 0.7us); barriers proven
// non-binding (R13). The lever left is resident-wave count. Hf halved to [64][64];
// each bucket: build Pl once, then {write Hf half, barrier, FMA half, barrier} x2.
// Same fp32 sums per cell (numerics identical).

union SmemU {
  uint4 stage[2048];                                   // 32 KB (MFMA staging phase)
  struct { float Hf[64 * 64]; float Pl[64 * 64]; } pg; // 32 KB (pool phase, j-halved)
};

__global__ void __launch_bounds__(256)
k_gemm_pg(const unsigned short* __restrict__ zhi, const unsigned short* __restrict__ zlo,
          const unsigned short* __restrict__ whi, const unsigned short* __restrict__ wlo,
          const float* __restrict__ bias, const int* __restrict__ outBL,
          const int* __restrict__ boffO, const int2* __restrict__ od,
          float* __restrict__ partials, int n) {
  __shared__ SmemU u;
  __shared__ float dinvL[128];
  const int t = threadIdx.x;
  const int l = t & 63, wv = t >> 6;
  const int wr = wv >> 1, wc = wv & 1;  // wave tile: 64x64 in a 2x2 wave grid
  const int lr = l & 15, lk = l >> 4;
  const int rowBase = blockIdx.x << 7;
  const bool full = (rowBase + 128 <= n);

  f32x4 acc[4][4];
#pragma unroll
  for (int mt = 0; mt < 4; mt++)
#pragma unroll
    for (int nt = 0; nt < 4; nt++) acc[mt][nt] = (f32x4){0.f, 0.f, 0.f, 0.f};

  for (int ch = 0; ch < 4; ch++) {  // K chunks of 32
    __syncthreads();
    if (full) {
#pragma unroll
      for (int i = 0; i < 2; i++) {  // stage A (hi+lo) async
        int s = t + (i << 8);        // 0..511
        int sl = s & 63, rt = s >> 6;
        int row = rowBase + (rt << 4) + (sl & 15);
        int kk = (ch << 5) + ((sl >> 4) << 3);
        gload16(&zhi[(size_t)row * 128 + kk], &u.stage[s]);
        gload16(&zlo[(size_t)row * 128 + kk], &u.stage[512 + s]);
      }
    } else {
#pragma unroll
      for (int i = 0; i < 2; i++) {  // tail block: predicated register path
        int s = t + (i << 8);
        int sl = s & 63, rt = s >> 6;
        int row = rowBase + (rt << 4) + (sl & 15);
        int kk = (ch << 5) + ((sl >> 4) << 3);
        uint4 vh = make_uint4(0u, 0u, 0u, 0u), vl = vh;
        if (row < n) {
          vh = *(const uint4*)&zhi[(size_t)row * 128 + kk];
          vl = *(const uint4*)&zlo[(size_t)row * 128 + kk];
        }
        u.stage[s] = vh;
        u.stage[512 + s] = vl;
      }
    }
#pragma unroll
    for (int i = 0; i < 2; i++) {  // stage W (hi+lo) async (no boundary)
      int s = t + (i << 8);
      int sl = s & 63, ct = s >> 6;
      int col = (ct << 4) + (sl & 15);
      int kk = (ch << 5) + ((sl >> 4) << 3);
      gload16(&whi[col * 128 + kk], &u.stage[1024 + s]);
      gload16(&wlo[col * 128 + kk], &u.stage[1536 + s]);
    }
    __syncthreads();

    bf16x8 ah[4], al[4], bh[4], bl[4];
#pragma unroll
    for (int mt = 0; mt < 4; mt++) {
      int slot = ((wr << 2) + mt) * 64 + l;
      ah[mt] = *(const bf16x8*)&u.stage[slot];
      al[mt] = *(const bf16x8*)&u.stage[512 + slot];
    }
#pragma unroll
    for (int nt = 0; nt < 4; nt++) {
      int slot = ((wc << 2) + nt) * 64 + l;
      bh[nt] = *(const bf16x8*)&u.stage[1024 + slot];
      bl[nt] = *(const bf16x8*)&u.stage[1536 + slot];
    }
#pragma unroll
    for (int mt = 0; mt < 4; mt++)
#pragma unroll
      for (int nt = 0; nt < 4; nt++) {
        acc[mt][nt] = __builtin_amdgcn_mfma_f32_16x16x32_bf16(ah[mt], bh[nt], acc[mt][nt], 0, 0, 0);
        acc[mt][nt] = __builtin_amdgcn_mfma_f32_16x16x32_bf16(ah[mt], bl[nt], acc[mt][nt], 0, 0, 0);
        acc[mt][nt] = __builtin_amdgcn_mfma_f32_16x16x32_bf16(al[mt], bh[nt], acc[mt][nt], 0, 0, 0);
      }
  }

  // bias + relu in registers (C/D layout: col = lane&15, row = (lane>>4)*4 + reg)
  float bv[4];
#pragma unroll
  for (int nt = 0; nt < 4; nt++) bv[nt] = bias[(wc << 6) + (nt << 4) + lr];
#pragma unroll
  for (int mt = 0; mt < 4; mt++)
#pragma unroll
    for (int nt = 0; nt < 4; nt++)
#pragma unroll
      for (int j = 0; j < 4; j++)
        acc[mt][nt][j] = fmaxf(acc[mt][nt][j] + bv[nt], 0.f);

  // dinvL for both buckets, once (visible after first pool barrier)
  if (t < 128) {
    int node = rowBase + t;
    dinvL[t] = (node < n) ? __int_as_float(od[node].y) : 0.f;
  }

  // ---- pool phase: per bucket, Pl built once; two j-halves through Hf[64][64] ----
  const int jq = t & 15;         // j-quad within 64-col half
  const int gg = (t >> 4) << 2;  // g group base
  float4 acc2[8];                // [jh*4 + gi]
#pragma unroll
  for (int i = 0; i < 8; i++) acc2[i] = make_float4(0.f, 0.f, 0.f, 0.f);

  for (int sub = 0; sub < 2; sub++) {
    const int base = rowBase + (sub << 6);
    __syncthreads();  // prior reads complete; dinvL visible (sub 0)
    for (int i4 = t; i4 < 1024; i4 += 256)
      ((float4*)u.pg.Pl)[i4] = make_float4(0.f, 0.f, 0.f, 0.f);
    __syncthreads();
    // concurrent: Hf write for jh=0 (wave wr==sub, wc==0) + P-tile atomics
    if (wr == sub && wc == 0) {
#pragma unroll
      for (int mt = 0; mt < 4; mt++)
#pragma unroll
        for (int j = 0; j < 4; j++) {
          int li = (mt << 4) + (lk << 2) + j;
          bool ok = (base + li) < n;
#pragma unroll
          for (int nt = 0; nt < 4; nt++)
            u.pg.Hf[li * 64 + (nt << 4) + lr] = ok ? acc[mt][nt][j] : 0.f;
        }
    }
    if (t < 64) {
      int node = base + t;
      if (node < n) {
        float dv = dinvL[(sub << 6) + t];
        atomicAdd(&u.pg.Pl[(t << 6) + (int)(((unsigned)od[node].x) >> 24)], dv * dv);
      }
    }
    int e0 = 0, e1 = 0;
    if (base < n) {
      int bi = base >> 6;
      e0 = boffO[bi];
      e1 = boffO[bi + 1];
    }
    const float* dL = &dinvL[sub << 6];
    for (int e = e0 + t; e < e1; e += 256) {
      int p = outBL[e];
      int2 oc = od[p >> 6];
      float w2 = dL[p & 63] * __int_as_float(oc.y);
      atomicAdd(&u.pg.Pl[((p & 63) << 6) + (int)(((unsigned)oc.x) >> 24)], w2);
    }
    __syncthreads();

#define FMA4(A, PV) \
  A.x = fmaf(PV, hv.x, A.x); A.y = fmaf(PV, hv.y, A.y); \
  A.z = fmaf(PV, hv.z, A.z); A.w = fmaf(PV, hv.w, A.w);
    // FMA j-half 0
#pragma unroll 4
    for (int i = 0; i < 64; i++) {
      float4 hv = *(const float4*)&u.pg.Hf[i * 64 + (jq << 2)];
      float4 pa = *(const float4*)&u.pg.Pl[i * 64 + gg];
      FMA4(acc2[0], pa.x) FMA4(acc2[1], pa.y) FMA4(acc2[2], pa.z) FMA4(acc2[3], pa.w)
    }
    __syncthreads();
    // Hf write for jh=1 (wave wr==sub, wc==1)
    if (wr == sub && wc == 1) {
#pragma unroll
      for (int mt = 0; mt < 4; mt++)
#pragma unroll
        for (int j = 0; j < 4; j++) {
          int li = (mt << 4) + (lk << 2) + j;
          bool ok = (base + li) < n;
#pragma unroll
          for (int nt = 0; nt < 4; nt++)
            u.pg.Hf[li * 64 + (nt << 4) + lr] = ok ? acc[mt][nt][j] : 0.f;
        }
    }
    __syncthreads();
    // FMA j-half 1
#pragma unroll 4
    for (int i = 0; i < 64; i++) {
      float4 hv = *(const float4*)&u.pg.Hf[i * 64 + (jq << 2)];
      float4 pa = *(const float4*)&u.pg.Pl[i * 64 + gg];
      FMA4(acc2[4], pa.x) FMA4(acc2[5], pa.y) FMA4(acc2[6], pa.z) FMA4(acc2[7], pa.w)
    }
#undef FMA4
  }

  float* dst = &partials[(size_t)blockIdx.x * (NGRAPH * HDIM)];
#pragma unroll
  for (int jh = 0; jh < 2; jh++)
#pragma unroll
    for (int gi = 0; gi < 4; gi++)
      *(float4*)&dst[(gg + gi) * HDIM + (jh << 6) + (jq << 2)] = acc2[(jh << 2) + gi];
}

// parallel partials reduce: grid (32, 8), block 256
__global__ void k_reduce(const float* __restrict__ partials, float* __restrict__ pooled,
                         int nparts) {
  int cell = blockIdx.x * 256 + threadIdx.x;
  int stride = gridDim.y;
  int p = blockIdx.y;
  float a0 = 0.f, a1 = 0.f, a2 = 0.f, a3 = 0.f;
  for (; p + 3 * stride < nparts; p += 4 * stride) {
    a0 += partials[(size_t)p * 8192 + cell];
    a1 += partials[(size_t)(p + stride) * 8192 + cell];
    a2 += partials[(size_t)(p + 2 * stride) * 8192 + cell];
    a3 += partials[(size_t)(p + 3 * stride) * 8192 + cell];
  }
  for (; p < nparts; p += stride) a0 += partials[(size_t)p * 8192 + cell];
  unsafeAtomicAdd(&pooled[cell], (a0 + a1) + (a2 + a3));
}

// fused tail: t1 = pooled/cnt @ W3 + b3 (in LDS), then out = t1 @ Wl + bl
__global__ void k_mid(const float* __restrict__ pooled, const int* __restrict__ batch, int n,
                      const float* __restrict__ W3, const float* __restrict__ b3,
                      const float* __restrict__ Wl, const float* __restrict__ bl,
                      float* __restrict__ out) {
  __shared__ float sh[HDIM];
  __shared__ float invSh;
  int g = blockIdx.x, j = threadIdx.x;
  if (j == 0) {
    int lo = 0, hi = n;
    while (lo < hi) { int m = (lo + hi) >> 1; if (batch[m] < g) lo = m + 1; else hi = m; }
    int a = lo;
    lo = 0; hi = n;
    while (lo < hi) { int m = (lo + hi) >> 1; if (batch[m] < g + 1) lo = m + 1; else hi = m; }
    invSh = 1.f / fmaxf((float)(lo - a), 1.f);
  }
  __syncthreads();
  float inv = invSh;
  float acc = 0.f;
  for (int k = 0; k < HDIM; k++) acc = fmaf(pooled[g * HDIM + k], W3[k * HDIM + j], acc);
  sh[j] = acc * inv + b3[j];
  __syncthreads();
  if (j < NCLASS) {
    float o = bl[j];
    for (int k = 0; k < HDIM; k++) o = fmaf(sh[k], Wl[k * NCLASS + j], o);
    out[g * NCLASS + j] = o;
  }
}

// ---------------- host ----------------

extern "C" void kernel_launch(void* const* d_in, const int* in_sizes, int n_in,
                              void* d_out, int out_size, void* d_ws, size_t ws_size,
                              hipStream_t stream) {
  const float* x   = (const float*)d_in[0];
  const int*   ei  = (const int*)d_in[1];
  const int*   bat = (const int*)d_in[2];
  const float* W1  = (const float*)d_in[3];
  const float* b1  = (const float*)d_in[4];
  const float* W2  = (const float*)d_in[5];
  const float* b2  = (const float*)d_in[6];
  const float* W3  = (const float*)d_in[7];
  const float* b3  = (const float*)d_in[8];
  const float* Wl  = (const float*)d_in[9];
  const float* bl  = (const float*)d_in[10];
  float* out = (float*)d_out;

  const int n = in_sizes[0];
  const int E = in_sizes[1] / 2;
  const int* rowv = ei;            // edge_index[0] : message source
  const int* colv = ei + E;        // edge_index[1] : aggregation destination
  const int NB = (n + 63) >> 6;    // 64-node buckets (<= MAXB for n <= 131072)
  const int cB = (E + 2047) / 2048;
  const int NSEG = (cB + 7) >> 3;  // 8-row segments for the hierarchical scan
  const int nPB = (n + 127) >> 7;  // fused gemm+pool blocks (128 rows = 2 buckets)

  char* w = (char*)d_ws;
  size_t o = 0;
  auto alloc = [&](size_t bytes) {
    size_t r = (o + 255) & ~(size_t)255;
    o = r + bytes;
    return r;
  };

  size_t o_pool  = alloc((size_t)NGRAPH * HDIM * 4);   // only zeroed buffer
  size_t zero_end = o;
  size_t o_histI = alloc((size_t)cB * NB * 4);         // ~2 MB
  size_t o_histO = alloc((size_t)cB * NB * 4);
  size_t o_segI  = alloc((size_t)NSEG * NB * 4);       // segment sums (~250 KB)
  size_t o_segO  = alloc((size_t)NSEG * NB * 4);
  size_t o_btotI = alloc((size_t)MAXB * 4);
  size_t o_btotO = alloc((size_t)MAXB * 4);
  size_t o_boffI = alloc((size_t)(MAXB + 1) * 4);
  size_t o_boffO = alloc((size_t)(MAXB + 1) * 4);
  size_t o_od    = alloc((size_t)n * 8);
  size_t o_dx    = alloc((size_t)n * 8);
  size_t o_sd    = alloc((size_t)n * 8);
  size_t o_wt    = alloc((size_t)HDIM * HDIM * 4);     // wthi + wtlo
  size_t o_gw    = alloc((size_t)E * 4);               // node-CSR (src)
  size_t o_inBL  = alloc((size_t)E * 4);               // dest-bucket list
  size_t o_outBL = alloc((size_t)E * 4);               // src-bucket list (4B payload)
  size_t o_part  = alloc((size_t)nPB * NGRAPH * HDIM * 4);  // partials (~25.6 MB)
  size_t o_bufB  = alloc((size_t)n * HDIM * 4);        // zhi+zlo (read by fused kernel)
  (void)n_in; (void)out_size; (void)ws_size;

  float*  pooled   = (float*)(w + o_pool);
  int*    histI    = (int*)(w + o_histI);
  int*    histO    = (int*)(w + o_histO);
  int*    segI     = (int*)(w + o_segI);
  int*    segO     = (int*)(w + o_segO);
  int*    btotI    = (int*)(w + o_btotI);
  int*    btotO    = (int*)(w + o_btotO);
  int*    boffI    = (int*)(w + o_boffI);
  int*    boffO    = (int*)(w + o_boffO);
  int2*   od       = (int2*)(w + o_od);
  float2* dx       = (float2*)(w + o_dx);
  float2* sd       = (float2*)(w + o_sd);
  unsigned short* wthi = (unsigned short*)(w + o_wt);
  unsigned short* wtlo = wthi + HDIM * HDIM;
  int*    gwi      = (int*)(w + o_gw);
  int*    inBL     = (int*)(w + o_inBL);
  int*    outBL    = (int*)(w + o_outBL);
  float*  partials = (float*)(w + o_part);
  unsigned short* zhi = (unsigned short*)(w + o_bufB);
  unsigned short* zlo = zhi + (size_t)n * HDIM;

  hipMemsetAsync(w + o_pool, 0, zero_end - o_pool, stream);

  const int gB = (NB + 255) / 256;
  // private-row histograms + W2^T split (no fabric atomics anywhere below)
  k_countw<<<cB + 64, 256, 0, stream>>>(colv, rowv, E, histI, histO, W2,
                                        wthi, wtlo, cB, NB);
  k_hA<<<dim3(gB, NSEG, 2), 256, 0, stream>>>(histI, histO, segI, segO, NB, cB);
  k_hB<<<dim3(gB, 2), 256, 0, stream>>>(segI, segO, btotI, btotO, NB, NSEG);
  k_hscanB<<<1, 1024, 0, stream>>>(btotI, boffI, btotO, boffO, NB, E);
  k_fill<<<cB, 256, 0, stream>>>(rowv, colv, E, histI, histO, segI, segO,
                                 boffI, boffO, inBL, outBL, NB);
  k_rank2x<<<NB, 256, 0, stream>>>(inBL, boffI, bat, x, od, dx, gwi, n);
  k_s<<<(n + 255) / 256, 256, 0, stream>>>(od, dx, gwi, sd, n, E);

  // fused rank-1 h1 + relu + layer-2 aggregation -> z as bf16 hi/lo
  k_l2in<<<(n + 3) / 4, 256, 0, stream>>>(sd, od, gwi, W1, b1,
                                          (ushort2*)zhi, (ushort2*)zlo, n, E);

  // FUSED layer-2 GEMM (MFMA, staged) + layer-3 pool (j-split, 4 blocks/CU)
  k_gemm_pg<<<nPB, 256, 0, stream>>>(zhi, zlo, wthi, wtlo, b2, outBL, boffO, od,
                                     partials, n);
  k_reduce<<<dim3(32, 8), 256, 0, stream>>>(partials, pooled, nPB);

  // fused tail: mid GEMM + classifier
  k_mid<<<NGRAPH, HDIM, 0, stream>>>(pooled, bat, n, W3, b3, Wl, bl, out);
}

// Round 16
// 233.017 us; speedup vs baseline: 1.0669x; 1.0669x over previous
//
#include <hip/hip_runtime.h>

#define HDIM 128
#define NGRAPH 64
#define NCLASS 7
#define MAXB 2048     // max 64-node buckets: supports n <= 131072

typedef __attribute__((ext_vector_type(8))) __bf16 bf16x8;
typedef __attribute__((ext_vector_type(4))) float f32x4;

__device__ __forceinline__ unsigned short bf16_rne(float f) {
  unsigned u = __float_as_uint(f);
  u += 0x7FFF + ((u >> 16) & 1);
  return (unsigned short)(u >> 16);
}

// async global->LDS 16B (direct-to-LDS, no VGPR round-trip). LDS dest must be
// wave-uniform base + lane*16 (our staging layouts satisfy this by construction).
__device__ __forceinline__ void gload16(const void* g, void* l) {
  __builtin_amdgcn_global_load_lds((const __attribute__((address_space(1))) void*)g,
                                   (__attribute__((address_space(3))) void*)l, 16, 0, 0);
}

// ---------------- ZERO-FABRIC-ATOMIC preprocessing (R8/R9) ----------------

// count pass: per-block LDS bucket histograms -> PRIVATE rows of hist[cB][NB] (no merges)
__global__ void k_countw(const int* __restrict__ col, const int* __restrict__ row, int E,
                         int* __restrict__ histI, int* __restrict__ histO,
                         const float* __restrict__ W,
                         unsigned short* __restrict__ wthi, unsigned short* __restrict__ wtlo,
                         int cB, int NB) {
  int b = blockIdx.x;
  if (b < cB) {
    __shared__ int binsI[MAXB], binsO[MAXB];
    int t = threadIdx.x;
    for (int i = t; i < NB; i += 256) { binsI[i] = 0; binsO[i] = 0; }
    __syncthreads();
    int base = b << 11;  // 2048 contiguous edges per block
#pragma unroll
    for (int j = 0; j < 8; j++) {
      int e = base + (j << 8) + t;
      if (e < E) {
        atomicAdd(&binsI[col[e] >> 6], 1);  // LDS only
        atomicAdd(&binsO[row[e] >> 6], 1);
      }
    }
    __syncthreads();
    for (int i = t; i < NB; i += 256) {
      histI[(size_t)b * NB + i] = binsI[i];  // plain coalesced writes
      histO[(size_t)b * NB + i] = binsO[i];
    }
  } else {
    int idx = (b - cB) * 256 + threadIdx.x;  // 0..16383
    int c = idx >> 7, k = idx & 127;
    float v = W[k * 128 + c];
    unsigned short h = bf16_rne(v);
    wthi[idx] = h;
    wtlo[idx] = bf16_rne(v - __uint_as_float((unsigned)h << 16));
  }
}

// segment scan: thread=(bucket, 8-row segment), register-staged loads (R9 fix).
__global__ void k_hA(int* __restrict__ histI, int* __restrict__ histO,
                     int* __restrict__ segI, int* __restrict__ segO,
                     int NB, int cB) {
  int bkt = blockIdx.x * 256 + threadIdx.x;
  if (bkt >= NB) return;
  int* hist = blockIdx.z ? histO : histI;
  int* segs = blockIdx.z ? segO : segI;
  int r0 = blockIdx.y << 3;
  int v[8];
#pragma unroll
  for (int j = 0; j < 8; j++) {
    int ri = r0 + j;
    v[j] = (ri < cB) ? hist[(size_t)ri * NB + bkt] : 0;
  }
  int s = 0;
#pragma unroll
  for (int j = 0; j < 8; j++) { int tv = v[j]; v[j] = s; s += tv; }
#pragma unroll
  for (int j = 0; j < 8; j++) {
    int ri = r0 + j;
    if (ri < cB) hist[(size_t)ri * NB + bkt] = v[j];
  }
  segs[(size_t)blockIdx.y * NB + bkt] = s;
}

// per-bucket scan of segment sums (register-chunked) -> seg bases + bucket totals
__global__ void k_hB(int* __restrict__ segI, int* __restrict__ segO,
                     int* __restrict__ btotI, int* __restrict__ btotO,
                     int NB, int NSEG) {
  int bkt = blockIdx.x * 256 + threadIdx.x;
  if (bkt >= NB) return;
  int* segs = blockIdx.y ? segO : segI;
  int* btot = blockIdx.y ? btotO : btotI;
  int run = 0;
  for (int c0 = 0; c0 < NSEG; c0 += 8) {
    int v[8];
#pragma unroll
    for (int j = 0; j < 8; j++) {
      int si = c0 + j;
      v[j] = (si < NSEG) ? segs[(size_t)si * NB + bkt] : 0;
    }
#pragma unroll
    for (int j = 0; j < 8; j++) { int tv = v[j]; v[j] = run; run += tv; }
#pragma unroll
    for (int j = 0; j < 8; j++) {
      int si = c0 + j;
      if (si < NSEG) segs[(size_t)si * NB + bkt] = v[j];
    }
  }
  btot[bkt] = run;
}

// single-block dual scan: bucket totals -> boff (exclusive, +E at [NB])
__global__ void k_hscanB(const int* __restrict__ btotI, int* __restrict__ boffI,
                         const int* __restrict__ btotO, int* __restrict__ boffO,
                         int NB, int E) {
  __shared__ int sh[1024];
  int t = threadIdx.x;
  for (int s = 0; s < 2; s++) {
    const int* src = s ? btotO : btotI;
    int* boff = s ? boffO : boffI;
    int i0 = 2 * t, i1 = 2 * t + 1;
    int a0 = (i0 < NB) ? src[i0] : 0;
    int a1 = (i1 < NB) ? src[i1] : 0;
    sh[t] = a0 + a1;
    __syncthreads();
    for (int o = 1; o < 1024; o <<= 1) {
      int v = (t >= o) ? sh[t - o] : 0;
      __syncthreads();
      sh[t] += v;
      __syncthreads();
    }
    int ex = (t == 0) ? 0 : sh[t - 1];
    if (i0 < NB) boff[i0] = ex;
    if (i1 < NB) boff[i1] = ex + a0;
    if (t == 0) boff[NB] = E;
    __syncthreads();
  }
}

// fill pass: positions entirely from LDS (boff + seg base + my-block rel + LDS rank).
__global__ void __launch_bounds__(256) k_fill(const int* __restrict__ row,
                                              const int* __restrict__ col, int E,
                                              const int* __restrict__ histI,
                                              const int* __restrict__ histO,
                                              const int* __restrict__ segI,
                                              const int* __restrict__ segO,
                                              const int* __restrict__ boffI,
                                              const int* __restrict__ boffO,
                                              int* __restrict__ inBL,
                                              int* __restrict__ outBL, int NB) {
  __shared__ int baseI[MAXB], baseO[MAXB], binsI[MAXB], binsO[MAXB];  // 32 KB
  int t = threadIdx.x, b = blockIdx.x;
  int sg = b >> 3;
  for (int i = t; i < NB; i += 256) {
    baseI[i] = boffI[i] + segI[(size_t)sg * NB + i] + histI[(size_t)b * NB + i];
    baseO[i] = boffO[i] + segO[(size_t)sg * NB + i] + histO[(size_t)b * NB + i];
    binsI[i] = 0;
    binsO[i] = 0;
  }
  __syncthreads();
  int base = b << 11;
#pragma unroll
  for (int j = 0; j < 8; j++) {
    int e = base + (j << 8) + t;
    if (e < E) {
      int r = row[e], c = col[e];
      int rkI = atomicAdd(&binsI[c >> 6], 1);  // LDS only
      int rkO = atomicAdd(&binsO[r >> 6], 1);
      inBL[baseI[c >> 6] + rkI] = (r << 6) | (c & 63);
      outBL[baseO[r >> 6] + rkO] = (c << 6) | (r & 63);
    }
  }
}

// per-bucket: count per-node (=> deg/dinv), LDS scan, node-CSR reorder into gwi,
// write od/dx with ABSOLUTE offsets.
__global__ void __launch_bounds__(256) k_rank2x(const int* __restrict__ inBL,
                                                const int* __restrict__ boffI,
                                                const int* __restrict__ batch,
                                                const float* __restrict__ x,
                                                int2* __restrict__ od,
                                                float2* __restrict__ dx,
                                                int* __restrict__ gwi, int n) {
  __shared__ int cnt[64], cnt2[64], loc[64], sc[64];
  int bi = blockIdx.x, t = threadIdx.x;
  if (t < 64) { cnt[t] = 0; cnt2[t] = 0; }
  __syncthreads();
  int e0 = boffI[bi], e1 = boffI[bi + 1];
  for (int e = e0 + t; e < e1; e += 256) atomicAdd(&cnt[inBL[e] & 63], 1);
  __syncthreads();
  if (t < 64) sc[t] = cnt[t];
  __syncthreads();
  for (int o = 1; o < 64; o <<= 1) {
    int v = (t < 64 && t >= o) ? sc[t - o] : 0;
    __syncthreads();
    if (t < 64) sc[t] += v;
    __syncthreads();
  }
  if (t < 64) {
    int excl = (t == 0) ? 0 : sc[t - 1];
    loc[t] = e0 + excl;
    int node = (bi << 6) + t;
    if (node < n) {
      int g = batch[node];
      float dinv = rsqrtf((float)(cnt[t] + 1));  // +1 self-loop
      od[node] = make_int2((e0 + excl) | (g << 24), __float_as_int(dinv));
      dx[node] = make_float2(dinv, x[node]);
    }
  }
  __syncthreads();
  for (int e = e0 + t; e < e1; e += 256) {
    int v = inBL[e];
    int dl = v & 63;
    int k = atomicAdd(&cnt2[dl], 1);
    gwi[loc[dl] + k] = v >> 6;
  }
}

// layer-1 aggregate by GATHER over in-CSR:
// sd[i] = { dinv^2 x_i + dinv * sum_r dinv_r x_r , dinv }
__global__ void k_s(const int2* __restrict__ od, const float2* __restrict__ dx,
                    const int* __restrict__ gwi, float2* __restrict__ sd, int n, int E) {
  int i = blockIdx.x * 256 + threadIdx.x;
  if (i >= n) return;
  int2 o2 = od[i];
  float dinv = __int_as_float(o2.y);
  int e0 = o2.x & 0xFFFFFF;
  int e1 = (i + 1 < n) ? (od[i + 1].x & 0xFFFFFF) : E;
  float s0 = 0.f, s1 = 0.f;
  int e = e0;
  for (; e + 2 <= e1; e += 2) {
    float2 a = dx[gwi[e]];
    float2 b = dx[gwi[e + 1]];
    s0 = fmaf(a.x, a.y, s0);
    s1 = fmaf(b.x, b.y, s1);
  }
  if (e < e1) { float2 a = dx[gwi[e]]; s0 = fmaf(a.x, a.y, s0); }
  float xv = dx[i].y;
  sd[i] = make_float2(fmaf(dinv * dinv, xv, dinv * (s0 + s1)), dinv);
}

// ---------------- fused: h1 = relu(s*W1+b1) recomputed per edge + agg2 ----------------
// Lane-parallel edge gather + register broadcast (R4). Output z as bf16 hi/lo.

__global__ void __launch_bounds__(256) k_l2in(const float2* __restrict__ sd,
                                              const int2* __restrict__ od,
                                              const int* __restrict__ gwi,
                                              const float* __restrict__ W1,
                                              const float* __restrict__ b1,
                                              ushort2* __restrict__ zhi,
                                              ushort2* __restrict__ zlo, int n, int E) {
  int node = blockIdx.x * 4 + (threadIdx.x >> 6);
  if (node >= n) return;
  int l = threadIdx.x & 63;
  float2 w1 = ((const float2*)W1)[l];
  float2 bv = ((const float2*)b1)[l];
  int2 on = od[node];
  float dstd = __int_as_float(on.y);
  float nself = dstd * dstd;
  float sv = sd[node].x;
  float2 acc;
  acc.x = nself * fmaxf(fmaf(sv, w1.x, bv.x), 0.f);
  acc.y = nself * fmaxf(fmaf(sv, w1.y, bv.y), 0.f);
  int e0 = on.x & 0xFFFFFF;
  int e1 = (node + 1 < n) ? (od[node + 1].x & 0xFFFFFF) : E;

  for (int eb = e0; eb < e1; eb += 64) {
    int m = e1 - eb; if (m > 64) m = 64;
    int ee = eb + l; if (ee >= e1) ee = e1 - 1;      // clamped, coalesced
    float2 q = sd[gwi[ee]];                          // per-lane independent gather
    float u = q.y * dstd;
    int k = 0;
    for (; k + 4 <= m; k += 4) {
      float q0 = __shfl(q.x, k),     u0 = __shfl(u, k);
      float q1 = __shfl(q.x, k + 1), u1 = __shfl(u, k + 1);
      float q2 = __shfl(q.x, k + 2), u2 = __shfl(u, k + 2);
      float q3 = __shfl(q.x, k + 3), u3 = __shfl(u, k + 3);
      acc.x = fmaf(u0, fmaxf(fmaf(q0, w1.x, bv.x), 0.f), acc.x);
      acc.y = fmaf(u0, fmaxf(fmaf(q0, w1.y, bv.y), 0.f), acc.y);
      acc.x = fmaf(u1, fmaxf(fmaf(q1, w1.x, bv.x), 0.f), acc.x);
      acc.y = fmaf(u1, fmaxf(fmaf(q1, w1.y, bv.y), 0.f), acc.y);
      acc.x = fmaf(u2, fmaxf(fmaf(q2, w1.x, bv.x), 0.f), acc.x);
      acc.y = fmaf(u2, fmaxf(fmaf(q2, w1.y, bv.y), 0.f), acc.y);
      acc.x = fmaf(u3, fmaxf(fmaf(q3, w1.x, bv.x), 0.f), acc.x);
      acc.y = fmaf(u3, fmaxf(fmaf(q3, w1.y, bv.y), 0.f), acc.y);
    }
    for (; k < m; k++) {
      float qk = __shfl(q.x, k), uk = __shfl(u, k);
      acc.x = fmaf(uk, fmaxf(fmaf(qk, w1.x, bv.x), 0.f), acc.x);
      acc.y = fmaf(uk, fmaxf(fmaf(qk, w1.y, bv.y), 0.f), acc.y);
    }
  }

  ushort2 h, lo;
  h.x = bf16_rne(acc.x);
  lo.x = bf16_rne(acc.x - __uint_as_float((unsigned)h.x << 16));
  h.y = bf16_rne(acc.y);
  lo.y = bf16_rne(acc.y - __uint_as_float((unsigned)h.y << 16));
  zhi[(size_t)node * 64 + l] = h;
  zlo[(size_t)node * 64 + l] = lo;
}

// ---------------- FUSED layer-2 GEMM + layer-3 pool ----------------
// R15: 512-THREAD blocks (8 waves), same 128-row tile & algorithm. Evidence from 4
// rounds: all pipes <26%, 970 GB/s, bank-conflicts/barriers/LDS-size all ruled out ->
// wave-starvation (12 waves/CU) is the last standing theory. Halving each wave's tile
// (4x2 wave grid, 32x64 MFMA tiles, acc[2][4]) doubles waves/CU at constant LDS
// (48.5KB -> 3 blocks/CU x 8 waves = 24/CU). Identical per-cell fp32 op order.
// R14's j-split REVERTED (LDS size proven non-binding; it regressed 60.4->66.8).

union SmemU {
  uint4 stage[2048];                                   // 32 KB (MFMA staging phase)
  struct { float Hf[64 * 128]; float Pl[64 * 64]; } pg;  // 48 KB (pool phase)
};

__global__ void __launch_bounds__(512, 5)
k_gemm_pg(const unsigned short* __restrict__ zhi, const unsigned short* __restrict__ zlo,
          const unsigned short* __restrict__ whi, const unsigned short* __restrict__ wlo,
          const float* __restrict__ bias, const int* __restrict__ outBL,
          const int* __restrict__ boffO, const int2* __restrict__ od,
          float* __restrict__ partials, int n) {
  __shared__ SmemU u;
  __shared__ float dinvL[128];
  const int t = threadIdx.x;
  const int l = t & 63, wv = t >> 6;
  const int wr = wv >> 1, wc = wv & 1;  // 4x2 wave grid: 32-row x 64-col tiles
  const int lr = l & 15, lk = l >> 4;
  const int rowBase = blockIdx.x << 7;
  const bool full = (rowBase + 128 <= n);

  f32x4 acc[2][4];
#pragma unroll
  for (int mt = 0; mt < 2; mt++)
#pragma unroll
    for (int nt = 0; nt < 4; nt++) acc[mt][nt] = (f32x4){0.f, 0.f, 0.f, 0.f};

  for (int ch = 0; ch < 4; ch++) {  // K chunks of 32
    __syncthreads();
    {
      int sl = t & 63, rt = t >> 6;  // slot = t: one pass covers each 512-slot region
      int row = rowBase + (rt << 4) + (sl & 15);
      int kk = (ch << 5) + ((sl >> 4) << 3);
      if (full) {
        gload16(&zhi[(size_t)row * 128 + kk], &u.stage[t]);
        gload16(&zlo[(size_t)row * 128 + kk], &u.stage[512 + t]);
      } else {
        uint4 vh = make_uint4(0u, 0u, 0u, 0u), vl = vh;
        if (row < n) {
          vh = *(const uint4*)&zhi[(size_t)row * 128 + kk];
          vl = *(const uint4*)&zlo[(size_t)row * 128 + kk];
        }
        u.stage[t] = vh;
        u.stage[512 + t] = vl;
      }
      int col = (rt << 4) + (sl & 15);  // W tile: same slot decomposition
      gload16(&whi[col * 128 + kk], &u.stage[1024 + t]);
      gload16(&wlo[col * 128 + kk], &u.stage[1536 + t]);
    }
    __syncthreads();

    bf16x8 ah[2], al[2];
#pragma unroll
    for (int mt = 0; mt < 2; mt++) {
      int slot = ((wr << 1) + mt) * 64 + l;
      ah[mt] = *(const bf16x8*)&u.stage[slot];
      al[mt] = *(const bf16x8*)&u.stage[512 + slot];
    }
#pragma unroll
    for (int nt = 0; nt < 4; nt++) {  // B fragments loaded per-nt (VGPR pressure)
      int slot = ((wc << 2) + nt) * 64 + l;
      bf16x8 bh = *(const bf16x8*)&u.stage[1024 + slot];
      bf16x8 bl = *(const bf16x8*)&u.stage[1536 + slot];
#pragma unroll
      for (int mt = 0; mt < 2; mt++) {
        acc[mt][nt] = __builtin_amdgcn_mfma_f32_16x16x32_bf16(ah[mt], bh, acc[mt][nt], 0, 0, 0);
        acc[mt][nt] = __builtin_amdgcn_mfma_f32_16x16x32_bf16(ah[mt], bl, acc[mt][nt], 0, 0, 0);
        acc[mt][nt] = __builtin_amdgcn_mfma_f32_16x16x32_bf16(al[mt], bh, acc[mt][nt], 0, 0, 0);
      }
    }
  }

  // bias + relu in registers (C/D layout: col = lane&15, row = (lane>>4)*4 + reg)
  float bv[4];
#pragma unroll
  for (int nt = 0; nt < 4; nt++) bv[nt] = bias[(wc << 6) + (nt << 4) + lr];
#pragma unroll
  for (int mt = 0; mt < 2; mt++)
#pragma unroll
    for (int nt = 0; nt < 4; nt++)
#pragma unroll
      for (int j = 0; j < 4; j++)
        acc[mt][nt][j] = fmaxf(acc[mt][nt][j] + bv[nt], 0.f);

  // dinvL for both buckets, once (visible after first pool barrier)
  if (t < 128) {
    int node = rowBase + t;
    dinvL[t] = (node < n) ? __int_as_float(od[node].y) : 0.f;
  }

  // ---- pool phase: per 64-row bucket, H-tile + P-tile in LDS, FMA accumulate ----
  const int jl = t & 31;   // j-quad 0..31
  const int gh = t >> 5;   // g-quad 0..15
  float4 acc2[4];
#pragma unroll
  for (int i = 0; i < 4; i++) acc2[i] = make_float4(0.f, 0.f, 0.f, 0.f);

  for (int sub = 0; sub < 2; sub++) {
    const int base = rowBase + (sub << 6);
    __syncthreads();  // prior reads complete; dinvL visible (sub 0)
    for (int i4 = t; i4 < 1024; i4 += 512)
      ((float4*)u.pg.Pl)[i4] = make_float4(0.f, 0.f, 0.f, 0.f);
    if ((wr >> 1) == sub) {  // the 4 waves owning rows [base, base+64)
#pragma unroll
      for (int mt = 0; mt < 2; mt++)
#pragma unroll
        for (int j = 0; j < 4; j++) {
          int li = ((wr & 1) << 5) + (mt << 4) + (lk << 2) + j;  // 0..63 local row
          bool ok = (base + li) < n;
#pragma unroll
          for (int nt = 0; nt < 4; nt++)
            u.pg.Hf[li * 128 + (wc << 6) + (nt << 4) + lr] = ok ? acc[mt][nt][j] : 0.f;
        }
    }
    __syncthreads();
    // atomics: self term + edge terms (commutative, single phase)
    if (t < 64) {
      int node = base + t;
      if (node < n) {
        float dv = dinvL[(sub << 6) + t];
        atomicAdd(&u.pg.Pl[(t << 6) + (int)(((unsigned)od[node].x) >> 24)], dv * dv);
      }
    }
    int e0 = 0, e1 = 0;
    if (base < n) {
      int bi = base >> 6;
      e0 = boffO[bi];
      e1 = boffO[bi + 1];
    }
    const float* dL = &dinvL[sub << 6];
    for (int e = e0 + t; e < e1; e += 512) {
      int p = outBL[e];
      int2 oc = od[p >> 6];
      float w2 = dL[p & 63] * __int_as_float(oc.y);
      atomicAdd(&u.pg.Pl[((p & 63) << 6) + (int)(((unsigned)oc.x) >> 24)], w2);
    }
    __syncthreads();

#define FMA4(A, PV) \
  A.x = fmaf(PV, hv.x, A.x); A.y = fmaf(PV, hv.y, A.y); \
  A.z = fmaf(PV, hv.z, A.z); A.w = fmaf(PV, hv.w, A.w);
#pragma unroll 4
    for (int i = 0; i < 64; i++) {
      float4 hv = *(const float4*)&u.pg.Hf[i * 128 + (jl << 2)];
      float4 pa = ((const float4*)u.pg.Pl)[i * 16 + gh];
      FMA4(acc2[0], pa.x) FMA4(acc2[1], pa.y) FMA4(acc2[2], pa.z) FMA4(acc2[3], pa.w)
    }
#undef FMA4
  }

  float* dst = &partials[(size_t)blockIdx.x * (NGRAPH * HDIM)];
#pragma unroll
  for (int gi = 0; gi < 4; gi++)
    *(float4*)&dst[((gh << 2) + gi) * HDIM + (jl << 2)] = acc2[gi];
}

// parallel partials reduce: grid (32, 8), block 256
__global__ void k_reduce(const float* __restrict__ partials, float* __restrict__ pooled,
                         int nparts) {
  int cell = blockIdx.x * 256 + threadIdx.x;
  int stride = gridDim.y;
  int p = blockIdx.y;
  float a0 = 0.f, a1 = 0.f, a2 = 0.f, a3 = 0.f;
  for (; p + 3 * stride < nparts; p += 4 * stride) {
    a0 += partials[(size_t)p * 8192 + cell];
    a1 += partials[(size_t)(p + stride) * 8192 + cell];
    a2 += partials[(size_t)(p + 2 * stride) * 8192 + cell];
    a3 += partials[(size_t)(p + 3 * stride) * 8192 + cell];
  }
  for (; p < nparts; p += stride) a0 += partials[(size_t)p * 8192 + cell];
  unsafeAtomicAdd(&pooled[cell], (a0 + a1) + (a2 + a3));
}

// fused tail: t1 = pooled/cnt @ W3 + b3 (in LDS), then out = t1 @ Wl + bl
__global__ void k_mid(const float* __restrict__ pooled, const int* __restrict__ batch, int n,
                      const float* __restrict__ W3, const float* __restrict__ b3,
                      const float* __restrict__ Wl, const float* __restrict__ bl,
                      float* __restrict__ out) {
  __shared__ float sh[HDIM];
  __shared__ float invSh;
  int g = blockIdx.x, j = threadIdx.x;
  if (j == 0) {
    int lo = 0, hi = n;
    while (lo < hi) { int m = (lo + hi) >> 1; if (batch[m] < g) lo = m + 1; else hi = m; }
    int a = lo;
    lo = 0; hi = n;
    while (lo < hi) { int m = (lo + hi) >> 1; if (batch[m] < g + 1) lo = m + 1; else hi = m; }
    invSh = 1.f / fmaxf((float)(lo - a), 1.f);
  }
  __syncthreads();
  float inv = invSh;
  float acc = 0.f;
  for (int k = 0; k < HDIM; k++) acc = fmaf(pooled[g * HDIM + k], W3[k * HDIM + j], acc);
  sh[j] = acc * inv + b3[j];
  __syncthreads();
  if (j < NCLASS) {
    float o = bl[j];
    for (int k = 0; k < HDIM; k++) o = fmaf(sh[k], Wl[k * NCLASS + j], o);
    out[g * NCLASS + j] = o;
  }
}

// ---------------- host ----------------

extern "C" void kernel_launch(void* const* d_in, const int* in_sizes, int n_in,
                              void* d_out, int out_size, void* d_ws, size_t ws_size,
                              hipStream_t stream) {
  const float* x   = (const float*)d_in[0];
  const int*   ei  = (const int*)d_in[1];
  const int*   bat = (const int*)d_in[2];
  const float* W1  = (const float*)d_in[3];
  const float* b1  = (const float*)d_in[4];
  const float* W2  = (const float*)d_in[5];
  const float* b2  = (const float*)d_in[6];
  const float* W3  = (const float*)d_in[7];
  const float* b3  = (const float*)d_in[8];
  const float* Wl  = (const float*)d_in[9];
  const float* bl  = (const float*)d_in[10];
  float* out = (float*)d_out;

  const int n = in_sizes[0];
  const int E = in_sizes[1] / 2;
  const int* rowv = ei;            // edge_index[0] : message source
  const int* colv = ei + E;        // edge_index[1] : aggregation destination
  const int NB = (n + 63) >> 6;    // 64-node buckets (<= MAXB for n <= 131072)
  const int cB = (E + 2047) / 2048;
  const int NSEG = (cB + 7) >> 3;  // 8-row segments for the hierarchical scan
  const int nPB = (n + 127) >> 7;  // fused gemm+pool blocks (128 rows = 2 buckets)

  char* w = (char*)d_ws;
  size_t o = 0;
  auto alloc = [&](size_t bytes) {
    size_t r = (o + 255) & ~(size_t)255;
    o = r + bytes;
    return r;
  };

  size_t o_pool  = alloc((size_t)NGRAPH * HDIM * 4);   // only zeroed buffer
  size_t zero_end = o;
  size_t o_histI = alloc((size_t)cB * NB * 4);         // ~2 MB
  size_t o_histO = alloc((size_t)cB * NB * 4);
  size_t o_segI  = alloc((size_t)NSEG * NB * 4);       // segment sums (~250 KB)
  size_t o_segO  = alloc((size_t)NSEG * NB * 4);
  size_t o_btotI = alloc((size_t)MAXB * 4);
  size_t o_btotO = alloc((size_t)MAXB * 4);
  size_t o_boffI = alloc((size_t)(MAXB + 1) * 4);
  size_t o_boffO = alloc((size_t)(MAXB + 1) * 4);
  size_t o_od    = alloc((size_t)n * 8);
  size_t o_dx    = alloc((size_t)n * 8);
  size_t o_sd    = alloc((size_t)n * 8);
  size_t o_wt    = alloc((size_t)HDIM * HDIM * 4);     // wthi + wtlo
  size_t o_gw    = alloc((size_t)E * 4);               // node-CSR (src)
  size_t o_inBL  = alloc((size_t)E * 4);               // dest-bucket list
  size_t o_outBL = alloc((size_t)E * 4);               // src-bucket list (4B payload)
  size_t o_part  = alloc((size_t)nPB * NGRAPH * HDIM * 4);  // partials (~25.6 MB)
  size_t o_bufB  = alloc((size_t)n * HDIM * 4);        // zhi+zlo (read by fused kernel)
  (void)n_in; (void)out_size; (void)ws_size;

  float*  pooled   = (float*)(w + o_pool);
  int*    histI    = (int*)(w + o_histI);
  int*    histO    = (int*)(w + o_histO);
  int*    segI     = (int*)(w + o_segI);
  int*    segO     = (int*)(w + o_segO);
  int*    btotI    = (int*)(w + o_btotI);
  int*    btotO    = (int*)(w + o_btotO);
  int*    boffI    = (int*)(w + o_boffI);
  int*    boffO    = (int*)(w + o_boffO);
  int2*   od       = (int2*)(w + o_od);
  float2* dx       = (float2*)(w + o_dx);
  float2* sd       = (float2*)(w + o_sd);
  unsigned short* wthi = (unsigned short*)(w + o_wt);
  unsigned short* wtlo = wthi + HDIM * HDIM;
  int*    gwi      = (int*)(w + o_gw);
  int*    inBL     = (int*)(w + o_inBL);
  int*    outBL    = (int*)(w + o_outBL);
  float*  partials = (float*)(w + o_part);
  unsigned short* zhi = (unsigned short*)(w + o_bufB);
  unsigned short* zlo = zhi + (size_t)n * HDIM;

  hipMemsetAsync(w + o_pool, 0, zero_end - o_pool, stream);

  const int gB = (NB + 255) / 256;
  // private-row histograms + W2^T split (no fabric atomics anywhere below)
  k_countw<<<cB + 64, 256, 0, stream>>>(colv, rowv, E, histI, histO, W2,
                                        wthi, wtlo, cB, NB);
  k_hA<<<dim3(gB, NSEG, 2), 256, 0, stream>>>(histI, histO, segI, segO, NB, cB);
  k_hB<<<dim3(gB, 2), 256, 0, stream>>>(segI, segO, btotI, btotO, NB, NSEG);
  k_hscanB<<<1, 1024, 0, stream>>>(btotI, boffI, btotO, boffO, NB, E);
  k_fill<<<cB, 256, 0, stream>>>(rowv, colv, E, histI, histO, segI, segO,
                                 boffI, boffO, inBL, outBL, NB);
  k_rank2x<<<NB, 256, 0, stream>>>(inBL, boffI, bat, x, od, dx, gwi, n);
  k_s<<<(n + 255) / 256, 256, 0, stream>>>(od, dx, gwi, sd, n, E);

  // fused rank-1 h1 + relu + layer-2 aggregation -> z as bf16 hi/lo
  k_l2in<<<(n + 3) / 4, 256, 0, stream>>>(sd, od, gwi, W1, b1,
                                          (ushort2*)zhi, (ushort2*)zlo, n, E);

  // FUSED layer-2 GEMM (MFMA, staged) + layer-3 pool: 512-thread blocks (8 waves)
  k_gemm_pg<<<nPB, 512, 0, stream>>>(zhi, zlo, wthi, wtlo, b2, outBL, boffO, od,
                                     partials, n);
  k_reduce<<<dim3(32, 8), 256, 0, stream>>>(partials, pooled, nPB);

  // fused tail: mid GEMM + classifier
  k_mid<<<NGRAPH, HDIM, 0, stream>>>(pooled, bat, n, W3, b3, Wl, bl, out);
}